// Round 9
// baseline (465.559 us; speedup 1.0000x reference)
//
#include <hip/hip_runtime.h>
#include <hip/hip_cooperative_groups.h>
#include <stdint.h>

namespace cg = cooperative_groups;

#define TOKENS 8192
#define EDIM 512
#define HNUM 8
#define RNUM 16
#define DDIM 64
#define KDIM 512

typedef short v8s __attribute__((ext_vector_type(8)));
typedef float v4f __attribute__((ext_vector_type(4)));

__device__ inline float b2f(unsigned short u) {
    union { unsigned int i; float f; } c; c.i = ((unsigned int)u) << 16; return c.f;
}
__device__ inline unsigned short f2b(float f) {
    union { float f; unsigned int i; } c; c.f = f;
    unsigned int i = c.i + 0x7fffu + ((c.i >> 16) & 1u);
    return (unsigned short)(i >> 16);
}

// async global->LDS, 16B per lane; LDS dest = wave-uniform base + lane*16
#define GLD16(dst, src) \
    __builtin_amdgcn_global_load_lds((__attribute__((address_space(1))) void*)(src), \
                                     (__attribute__((address_space(3))) void*)(dst), 16, 0, 0)

__device__ __forceinline__ void cvt_chunk(unsigned short* __restrict__ d,
                                          const float* __restrict__ s, size_t base) {
    const float4* sp = (const float4*)(s + base);
    float4 f0 = sp[0], f1 = sp[1];
    v8s o;
    o[0] = (short)f2b(f0.x); o[1] = (short)f2b(f0.y);
    o[2] = (short)f2b(f0.z); o[3] = (short)f2b(f0.w);
    o[4] = (short)f2b(f1.x); o[5] = (short)f2b(f1.y);
    o[6] = (short)f2b(f1.z); o[7] = (short)f2b(f1.w);
    *(v8s*)(d + base) = o;
}

// ---- S0: fp32->bf16 convert, job = 2048-element block. 6400 jobs total ----
__device__ __forceinline__ void stage_cvt(int job, int tid,
    const float* __restrict__ query, const float* __restrict__ value,
    const float* __restrict__ Wv, const float* __restrict__ Wq,
    const float* __restrict__ Wo,
    unsigned short* __restrict__ qbf, unsigned short* __restrict__ vbf,
    unsigned short* __restrict__ Wvb, unsigned short* __restrict__ Wqb,
    unsigned short* __restrict__ Wob)
{
    const float* s; unsigned short* d; int local;
    if (job < 2048)      { s = query; d = qbf; local = job; }
    else if (job < 4096) { s = value; d = vbf; local = job - 2048; }
    else if (job < 6144) { s = Wv;    d = Wvb; local = job - 4096; }
    else if (job < 6272) { s = Wq;    d = Wqb; local = job - 6144; }
    else                 { s = Wo;    d = Wob; local = job - 6272; }
    cvt_chunk(d, s, (size_t)local * 2048 + (size_t)tid * 8);
}

// ---- S1+S2 fused: Q-GEMM 64x64 tile (64 tokens x head vb&7) + rules + softmax.
// LDS (16 KB): K-loop As@0 4KB, Bs@4096 4KB; after: rkl@0, iwl@4352, qsb@8704.
__device__ __forceinline__ void stage_qrules(char* smem, int vb, int tid,
    const unsigned short* __restrict__ qbf, const unsigned short* __restrict__ Wqb,
    const float* __restrict__ bq, const float* __restrict__ rk,
    const float* __restrict__ rw, float* __restrict__ attn)
{
    unsigned short* As = (unsigned short*)smem;
    unsigned short* Bs = (unsigned short*)(smem + 4096);
    float* rkl = (float*)smem;                      // stride 68 floats
    float* iwl = (float*)(smem + 4352);
    unsigned short* qsb = (unsigned short*)(smem + 8704);   // 64 x 40 shorts

    const int w = tid >> 6, lane = tid & 63, quad = lane >> 4, l16 = lane & 15;
    const int wm = w >> 1, wn = w & 1;
    const int swz = quad ^ ((l16 >> 1) & 3);
    const int t0 = (vb >> 3) * 64;
    const int h  = vb & 7;
    const int n0 = h * 64;

    __syncthreads();   // protect LDS from previous virtual tile

    v4f acc[2][2];
#pragma unroll
    for (int i = 0; i < 2; ++i)
#pragma unroll
        for (int j = 0; j < 2; ++j)
            acc[i][j] = (v4f){0.f, 0.f, 0.f, 0.f};

    for (int kt = 0; kt < KDIM / 32; ++kt) {
        int c   = w * 64 + lane;
        int row = c >> 2;
        int cc  = (c & 3) ^ ((c >> 3) & 3);
        GLD16(&As[w * 512], qbf + (size_t)(t0 + row) * KDIM + kt * 32 + cc * 8);
        GLD16(&Bs[w * 512], Wqb + (size_t)(n0 + row) * KDIM + kt * 32 + cc * 8);
        __syncthreads();
        v8s af[2], bf[2];
#pragma unroll
        for (int mt = 0; mt < 2; ++mt)
            af[mt] = *(const v8s*)&As[(wm * 32 + mt * 16 + l16) * 32 + swz * 8];
#pragma unroll
        for (int nt = 0; nt < 2; ++nt)
            bf[nt] = *(const v8s*)&Bs[(wn * 32 + nt * 16 + l16) * 32 + swz * 8];
#pragma unroll
        for (int mt = 0; mt < 2; ++mt)
#pragma unroll
            for (int nt = 0; nt < 2; ++nt)
                acc[mt][nt] = __builtin_amdgcn_mfma_f32_16x16x32_bf16(af[mt], bf[nt], acc[mt][nt], 0, 0, 0);
        __syncthreads();
    }

    // load rules (over As/Bs) + write q tile as bf16
#pragma unroll
    for (int i = 0; i < 4; ++i) {
        int jj = tid + i * 256;
        int r = jj >> 6, dd = jj & 63;
        rkl[r * 68 + dd] = rk[h * (RNUM * DDIM) + jj];
        float wv = rw[h * (RNUM * DDIM) + jj];
        iwl[r * 68 + dd] = 1.0f / (wv * wv);
    }
#pragma unroll
    for (int mt = 0; mt < 2; ++mt)
#pragma unroll
        for (int nt = 0; nt < 2; ++nt) {
            int col = wn * 32 + nt * 16 + l16;
            float bb = bq[n0 + col];
#pragma unroll
            for (int rg = 0; rg < 4; ++rg) {
                int row = wm * 32 + mt * 16 + quad * 4 + rg;
                qsb[row * 40 + col] = f2b((acc[mt][nt][rg] + bb) * 0.125f);
            }
        }
    __syncthreads();

    // rules + softmax: 4 passes x (16 tokens x 16 rules)
    const int grp = tid >> 4;
    const int r   = tid & 15;
    const float* krow = &rkl[r * 68];
    const float* wrow = &iwl[r * 68];
#pragma unroll
    for (int p = 0; p < 4; ++p) {
        int tok = p * 16 + grp;
        const unsigned short* qrow = &qsb[tok * 40];
        float z = 0.f;
#pragma unroll
        for (int c8 = 0; c8 < 8; ++c8) {
            v8s qv8 = *(const v8s*)&qrow[c8 * 8];
#pragma unroll
            for (int j = 0; j < 8; ++j) {
                int dd = c8 * 8 + j;
                float a = b2f((unsigned short)qv8[j]) - krow[dd];
                z += a * a * wrow[dd];
            }
        }
        z *= (-0.5f / 64.f);
        float mx = z;
#pragma unroll
        for (int s = 1; s < 16; s <<= 1) mx = fmaxf(mx, __shfl_xor(mx, s));
        float e = __expf(z - mx);
        float sum = e;
#pragma unroll
        for (int s = 1; s < 16; s <<= 1) sum += __shfl_xor(sum, s);
        attn[(size_t)(t0 + tok) * (HNUM * RNUM) + h * RNUM + r] = e / sum;
    }
}

// ---- S3: transposed V-GEMM 128x128 tile + rule contraction -> scrambled out1.
// LDS (16 KB): As@0 8KB, Bs@8192 8KB; Os (2 KB) aliases As after final barrier.
__device__ __forceinline__ void stage_vgemm(char* smem, int vb, int tid,
    const unsigned short* __restrict__ Wvb, const unsigned short* __restrict__ vbf,
    const float* __restrict__ bv, const float* __restrict__ attn,
    unsigned short* __restrict__ out1)
{
    unsigned short* As = (unsigned short*)smem;
    unsigned short* Bs = (unsigned short*)(smem + 8192);
    unsigned short* Os = (unsigned short*)smem;     // alias, used after barrier

    const int w = tid >> 6, lane = tid & 63, quad = lane >> 4, l16 = lane & 15;
    const int wm = w >> 1, wn = w & 1;
    const int swz = quad ^ ((l16 >> 1) & 3);
    const int m0 = (vb >> 6) * 128;    // Wv row base (h*1024 + d*16 + r)
    const int n0 = (vb & 63) * 128;    // token base

    __syncthreads();   // protect LDS from previous virtual tile

    v4f acc[4][4];
#pragma unroll
    for (int i = 0; i < 4; ++i)
#pragma unroll
        for (int j = 0; j < 4; ++j)
            acc[i][j] = (v4f){0.f, 0.f, 0.f, 0.f};

    for (int kt = 0; kt < KDIM / 32; ++kt) {
#pragma unroll
        for (int p = 0; p < 2; ++p) {
            int cb  = w * 128 + p * 64;
            int c   = cb + lane;
            int row = c >> 2;
            int cc  = (c & 3) ^ ((c >> 3) & 3);
            GLD16(&As[cb * 8], Wvb + (size_t)(m0 + row) * KDIM + kt * 32 + cc * 8);
            GLD16(&Bs[cb * 8], vbf + (size_t)(n0 + row) * KDIM + kt * 32 + cc * 8);
        }
        __syncthreads();
        v8s af[4], bf[4];
#pragma unroll
        for (int mt = 0; mt < 4; ++mt)
            af[mt] = *(const v8s*)&As[(wm * 64 + mt * 16 + l16) * 32 + swz * 8];
#pragma unroll
        for (int nt = 0; nt < 4; ++nt)
            bf[nt] = *(const v8s*)&Bs[(wn * 64 + nt * 16 + l16) * 32 + swz * 8];
#pragma unroll
        for (int mt = 0; mt < 4; ++mt)
#pragma unroll
            for (int nt = 0; nt < 4; ++nt)
                acc[mt][nt] = __builtin_amdgcn_mfma_f32_16x16x32_bf16(af[mt], bf[nt], acc[mt][nt], 0, 0, 0);
        __syncthreads();
    }

    const int h  = m0 >> 10;
    const int d0 = (m0 >> 4) & 63;
    float4 bias4[4];
#pragma unroll
    for (int mt = 0; mt < 4; ++mt)
        bias4[mt] = *(const float4*)&bv[m0 + wm * 64 + mt * 16 + quad * 4];
#pragma unroll
    for (int nt = 0; nt < 4; ++nt) {
        int token = n0 + wn * 64 + nt * 16 + l16;
        float4 av = *(const float4*)&attn[(size_t)token * (HNUM * RNUM) + h * RNUM + quad * 4];
#pragma unroll
        for (int mt = 0; mt < 4; ++mt) {
            v4f a = acc[mt][nt];
            float val = (a[0] + bias4[mt].x) * av.x
                      + (a[1] + bias4[mt].y) * av.y
                      + (a[2] + bias4[mt].z) * av.z
                      + (a[3] + bias4[mt].w) * av.w;
            val += __shfl_xor(val, 16);
            val += __shfl_xor(val, 32);
            if (quad == 0)
                Os[(wn * 64 + nt * 16 + l16) * 8 + (wm * 4 + mt)] = f2b(val * 0.125f);
        }
    }
    __syncthreads();
    if (tid < 128) {
        int sg = n0 + tid;
        int g  = (sg >> 11) * 2048 + h * 256 + ((sg & 2047) >> 3);
        int j  = (sg & 7) * 64 + d0;
        *(v8s*)&out1[(size_t)g * EDIM + j] = *(const v8s*)&Os[tid * 8];
    }
}

// ---- S4: O-GEMM 64x64 tile -> outF = C + bo ----
__device__ __forceinline__ void stage_ogemm(char* smem, int vb, int tid,
    const unsigned short* __restrict__ out1, const unsigned short* __restrict__ Wob,
    const float* __restrict__ bo, float* __restrict__ outF)
{
    unsigned short* As = (unsigned short*)smem;
    unsigned short* Bs = (unsigned short*)(smem + 4096);

    const int w = tid >> 6, lane = tid & 63, quad = lane >> 4, l16 = lane & 15;
    const int wm = w >> 1, wn = w & 1;
    const int swz = quad ^ ((l16 >> 1) & 3);
    const int m0 = (vb >> 3) * 64;
    const int n0 = (vb & 7) * 64;

    __syncthreads();

    v4f acc[2][2];
#pragma unroll
    for (int i = 0; i < 2; ++i)
#pragma unroll
        for (int j = 0; j < 2; ++j)
            acc[i][j] = (v4f){0.f, 0.f, 0.f, 0.f};

    for (int kt = 0; kt < KDIM / 32; ++kt) {
        int c   = w * 64 + lane;
        int row = c >> 2;
        int cc  = (c & 3) ^ ((c >> 3) & 3);
        GLD16(&As[w * 512], out1 + (size_t)(m0 + row) * KDIM + kt * 32 + cc * 8);
        GLD16(&Bs[w * 512], Wob  + (size_t)(n0 + row) * KDIM + kt * 32 + cc * 8);
        __syncthreads();
        v8s af[2], bf[2];
#pragma unroll
        for (int mt = 0; mt < 2; ++mt)
            af[mt] = *(const v8s*)&As[(wm * 32 + mt * 16 + l16) * 32 + swz * 8];
#pragma unroll
        for (int nt = 0; nt < 2; ++nt)
            bf[nt] = *(const v8s*)&Bs[(wn * 32 + nt * 16 + l16) * 32 + swz * 8];
#pragma unroll
        for (int mt = 0; mt < 2; ++mt)
#pragma unroll
            for (int nt = 0; nt < 2; ++nt)
                acc[mt][nt] = __builtin_amdgcn_mfma_f32_16x16x32_bf16(af[mt], bf[nt], acc[mt][nt], 0, 0, 0);
        __syncthreads();
    }
#pragma unroll
    for (int mt = 0; mt < 2; ++mt)
#pragma unroll
        for (int nt = 0; nt < 2; ++nt) {
            int col = n0 + wn * 32 + nt * 16 + l16;
            float bb = bo[col];
#pragma unroll
            for (int rg = 0; rg < 4; ++rg) {
                int row = m0 + wm * 32 + mt * 16 + quad * 4 + rg;
                outF[(size_t)row * EDIM + col] = acc[mt][nt][rg] + bb;
            }
        }
}

// ================= cooperative mega-kernel (grid-stride stages) =================
__global__ __launch_bounds__(256, 4)
void fuzzy_all(const float* query, const float* value,
               const float* Wq, const float* bq,
               const float* Wv, const float* bv,
               const float* Wo, const float* bo,
               const float* rk, const float* rw,
               unsigned short* qbf, unsigned short* vbf,
               unsigned short* Wqb, unsigned short* Wvb, unsigned short* Wob,
               float* attn, unsigned short* out1, float* outF)
{
    __shared__ __align__(16) char smem[16384];
    cg::grid_group grid = cg::this_grid();
    const int tid = threadIdx.x;
    const int bid = blockIdx.x;
    const int nb  = gridDim.x;

    for (int job = bid; job < 6400; job += nb)
        stage_cvt(job, tid, query, value, Wv, Wq, Wo, qbf, vbf, Wvb, Wqb, Wob);
    grid.sync();

    for (int vb = bid; vb < 1024; vb += nb)
        stage_qrules(smem, vb, tid, qbf, Wqb, bq, rk, rw, attn);
    grid.sync();

    for (int vb = bid; vb < 4096; vb += nb)
        stage_vgemm(smem, vb, tid, Wvb, vbf, bv, attn, out1);
    grid.sync();

    for (int vb = bid; vb < 1024; vb += nb)
        stage_ogemm(smem, vb, tid, out1, Wob, bo, outF);
}

// ================= fallback plain kernels (same stage bodies) =================
__global__ __launch_bounds__(256)
void k_cvt(const float* query, const float* value, const float* Wv,
           const float* Wq, const float* Wo,
           unsigned short* qbf, unsigned short* vbf, unsigned short* Wvb,
           unsigned short* Wqb, unsigned short* Wob)
{
    stage_cvt(blockIdx.x, threadIdx.x, query, value, Wv, Wq, Wo, qbf, vbf, Wvb, Wqb, Wob);
}
__global__ __launch_bounds__(256, 4)
void k_qrules(const unsigned short* qbf, const unsigned short* Wqb,
              const float* bq, const float* rk, const float* rw, float* attn)
{
    __shared__ __align__(16) char smem[16384];
    stage_qrules(smem, blockIdx.x, threadIdx.x, qbf, Wqb, bq, rk, rw, attn);
}
__global__ __launch_bounds__(256, 4)
void k_vgemm(const unsigned short* Wvb, const unsigned short* vbf,
             const float* bv, const float* attn, unsigned short* out1)
{
    __shared__ __align__(16) char smem[16384];
    stage_vgemm(smem, blockIdx.x, threadIdx.x, Wvb, vbf, bv, attn, out1);
}
__global__ __launch_bounds__(256, 4)
void k_ogemm(const unsigned short* out1, const unsigned short* Wob,
             const float* bo, float* outF)
{
    __shared__ __align__(16) char smem[16384];
    stage_ogemm(smem, blockIdx.x, threadIdx.x, out1, Wob, bo, outF);
}

extern "C" void kernel_launch(void* const* d_in, const int* in_sizes, int n_in,
                              void* d_out, int out_size, void* d_ws, size_t ws_size,
                              hipStream_t stream) {
    const float* query = (const float*)d_in[0];
    // d_in[1] = key (unused by the reference)
    const float* value = (const float*)d_in[2];
    const float* Wq = (const float*)d_in[3];
    const float* bq = (const float*)d_in[4];
    const float* Wv = (const float*)d_in[5];
    const float* bv = (const float*)d_in[6];
    const float* Wo = (const float*)d_in[7];
    const float* bo = (const float*)d_in[8];
    const float* rk = (const float*)d_in[9];
    const float* rw = (const float*)d_in[10];

    char* ws = (char*)d_ws;
    unsigned short* vbf  = (unsigned short*)(ws);                       //  8 MiB
    unsigned short* Wvb  = (unsigned short*)(ws + (size_t)( 8 << 20));  //  8 MiB
    unsigned short* Wob  = (unsigned short*)(ws + (size_t)(16 << 20));  // 0.5 MiB
    unsigned short* out1 = (unsigned short*)(ws + (size_t)(17 << 20));  //  8 MiB
    float* attn          = (float*)(ws + (size_t)(25 << 20));           //  4 MiB
    unsigned short* qbf  = (unsigned short*)(ws + (size_t)(29 << 20));  //  8 MiB
    unsigned short* Wqb  = (unsigned short*)(ws + (size_t)(37 << 20));  // 0.5 MiB
    float* outF          = (float*)d_out;

    // adaptive cooperative grid (pure occupancy query; graph-safe)
    int maxB = 0;
    hipError_t qerr = hipOccupancyMaxActiveBlocksPerMultiprocessor(&maxB, fuzzy_all, 256, 0);
    int grid = 1024;
    if (qerr == hipSuccess && maxB > 0 && maxB * 256 < grid) grid = maxB * 256;

    void* args[] = {
        (void*)&query, (void*)&value, (void*)&Wq, (void*)&bq, (void*)&Wv, (void*)&bv,
        (void*)&Wo, (void*)&bo, (void*)&rk, (void*)&rw,
        (void*)&qbf, (void*)&vbf, (void*)&Wqb, (void*)&Wvb, (void*)&Wob,
        (void*)&attn, (void*)&out1, (void*)&outF
    };
    hipError_t err = hipLaunchCooperativeKernel((const void*)fuzzy_all, dim3(grid),
                                                dim3(256), args, 0, stream);
    if (err != hipSuccess) {
        (void)hipGetLastError();   // clear error state
        dim3 blk(256);
        k_cvt<<<dim3(6400), blk, 0, stream>>>(query, value, Wv, Wq, Wo,
                                              qbf, vbf, Wvb, Wqb, Wob);
        k_qrules<<<dim3(1024), blk, 0, stream>>>(qbf, Wqb, bq, rk, rw, attn);
        k_vgemm<<<dim3(4096), blk, 0, stream>>>(Wvb, vbf, bv, attn, out1);
        k_ogemm<<<dim3(1024), blk, 0, stream>>>(out1, Wob, bo, outF);
    }
}